// Round 6
// baseline (595.756 us; speedup 1.0000x reference)
//
#include <hip/hip_runtime.h>

#define F_IN 500
#define HDIM 64
#define CDIM 10
#define KPAD 512           // K padded to 16 MFMA stages of 32
#define NSTAGE 16
#define H2LD 16            // padded h2s row stride (64 B lines)

typedef __attribute__((ext_vector_type(8))) short bf16x8;
typedef __attribute__((ext_vector_type(4))) float floatx4;

// RNE fp32 -> bf16 bits
__device__ inline unsigned short f2bf(float f) {
    unsigned int u = __float_as_uint(f);
    u += 0x7fffu + ((u >> 16) & 1u);
    return (unsigned short)(u >> 16);
}
__device__ inline float bflo(unsigned int u) { return __uint_as_float(u << 16); }
__device__ inline float bfhi(unsigned int u) { return __uint_as_float(u & 0xffff0000u); }

// ---------------------------------------------------------------------------
// Stage 1: in-degree histogram (self-loop handled as +1 in rsqrt)
// ---------------------------------------------------------------------------
__global__ void deg_count_kernel(const int* __restrict__ dst, int E,
                                 int* __restrict__ deg) {
    int e = blockIdx.x * blockDim.x + threadIdx.x;
    if (e < E) atomicAdd(&deg[dst[e]], 1);
}

// ---------------------------------------------------------------------------
// Stage 2: per-block exclusive scan deg -> row_ptr partials; dis fused.
// Final row_ptr[i] = row_ptr[i] + blk_sum[i>>10]; consumers do the add.
// ---------------------------------------------------------------------------
__global__ void scan_block_kernel(const int* __restrict__ deg,
                                  int* __restrict__ row_ptr,
                                  int* __restrict__ blk_sum,
                                  float* __restrict__ dis, int Np1) {
    __shared__ int wsum[16];
    int i = blockIdx.x * 1024 + threadIdx.x;
    int v = (i < Np1 - 1) ? deg[i] : 0;
    if (i < Np1 - 1) dis[i] = rsqrtf((float)(v + 1));
    int lane = threadIdx.x & 63;
    int wid = threadIdx.x >> 6;
    int x = v;
#pragma unroll
    for (int off = 1; off < 64; off <<= 1) {
        int y = __shfl_up(x, off);
        if (lane >= off) x += y;
    }
    if (lane == 63) wsum[wid] = x;
    __syncthreads();
    if (threadIdx.x < 16) {
        int ws = wsum[threadIdx.x];
#pragma unroll
        for (int off = 1; off < 16; off <<= 1) {
            int y = __shfl_up(ws, off);
            if ((int)threadIdx.x >= off) ws += y;
        }
        wsum[threadIdx.x] = ws;
    }
    __syncthreads();
    int wp = (wid > 0) ? wsum[wid - 1] : 0;
    if (i < Np1) row_ptr[i] = wp + x - v;
    if (threadIdx.x == 1023) blk_sum[blockIdx.x] = wp + x;
}

__global__ void scan_top_kernel(int* __restrict__ blk_sum, int nb) {
    int carry = 0;
    for (int base = 0; base < nb; base += 64) {
        int i = base + (int)threadIdx.x;
        int v = (i < nb) ? blk_sum[i] : 0;
        int x = v;
#pragma unroll
        for (int off = 1; off < 64; off <<= 1) {
            int y = __shfl_up(x, off);
            if ((int)threadIdx.x >= off) x += y;
        }
        if (i < nb) blk_sum[i] = carry + x - v;
        carry += __shfl(x, 63);
    }
}

// ---------------------------------------------------------------------------
// Stage 3: CSR fill (row base = partial row_ptr + blk_sum)
// ---------------------------------------------------------------------------
__global__ void csr_fill_kernel(const int* __restrict__ src,
                                const int* __restrict__ dst,
                                const int* __restrict__ row_ptr,
                                const int* __restrict__ blk_sum,
                                int* __restrict__ cursor,
                                int* __restrict__ csr_src, int E) {
    int e = blockIdx.x * blockDim.x + threadIdx.x;
    if (e >= E) return;
    int d = dst[e];
    int pos = atomicAdd(&cursor[d], 1);
    csr_src[row_ptr[d] + blk_sum[d >> 10] + pos] = src[e];
}

// ---------------------------------------------------------------------------
// W prep: split W1 into truncated-bf16 hi + bf16 residual in B-fragment order
// ---------------------------------------------------------------------------
__global__ void wprep_kernel(const float* __restrict__ W1,
                             unsigned short* __restrict__ whf,
                             unsigned short* __restrict__ wlf) {
    int idx = blockIdx.x * 256 + threadIdx.x;  // over KPAD*HDIM = 32768
    if (idx >= KPAD * HDIM) return;
    int k = idx >> 6;
    int f = idx & 63;
    float w = (k < F_IN) ? W1[k * HDIM + f] : 0.f;
    unsigned int b = __float_as_uint(w);
    unsigned short hh = (unsigned short)(b >> 16);
    float wl = w - __uint_as_float(b & 0xffff0000u);
    unsigned short ll = (unsigned short)(__float_as_uint(wl) >> 16);
    int kb = k >> 5, q = (k >> 3) & 3, j = k & 7;
    int fb = f >> 4, fl = f & 15;
    int lane = (q << 4) | fl;
    size_t o = ((((size_t)kb * 4 + fb) * 64 + lane) << 3) | (size_t)j;
    whf[o] = hh;
    wlf[o] = ll;
}

// ---------------------------------------------------------------------------
// Stage 4: h1 = x @ W1 via bf16 MFMA, 3-pass split; stores bf16(h1*dis[n]).
// ---------------------------------------------------------------------------
__global__ __launch_bounds__(256) void gemm1_kernel(
        const float* __restrict__ x,
        const unsigned short* __restrict__ whf,
        const unsigned short* __restrict__ wlf,
        const float* __restrict__ dis,
        unsigned short* __restrict__ h1b, int N) {
    const int lane = threadIdx.x & 63;
    const int wid = (blockIdx.x * 256 + threadIdx.x) >> 6;
    const int n0 = wid * 32;
    if (n0 >= N) return;
    const int q = lane >> 4;
    const int fl = lane & 15;

    int r0 = n0 + fl;       if (r0 >= N) r0 = N - 1;
    int r1 = n0 + 16 + fl;  if (r1 >= N) r1 = N - 1;
    const float* xp0 = x + (size_t)r0 * F_IN + q * 8;
    const float* xp1 = x + (size_t)r1 * F_IN + q * 8;

    floatx4 acc[2][4];
#pragma unroll
    for (int t = 0; t < 2; ++t)
#pragma unroll
        for (int fb = 0; fb < 4; ++fb) acc[t][fb] = (floatx4){0.f, 0.f, 0.f, 0.f};

    const bf16x8* whv = (const bf16x8*)whf;
    const bf16x8* wlv = (const bf16x8*)wlf;

    for (int kb = 0; kb < NSTAGE; ++kb) {
        float xv0[8], xv1[8];
        if (kb < NSTAGE - 1) {
            float4 a = *(const float4*)(xp0 + kb * 32);
            float4 b = *(const float4*)(xp0 + kb * 32 + 4);
            xv0[0] = a.x; xv0[1] = a.y; xv0[2] = a.z; xv0[3] = a.w;
            xv0[4] = b.x; xv0[5] = b.y; xv0[6] = b.z; xv0[7] = b.w;
            float4 c = *(const float4*)(xp1 + kb * 32);
            float4 d = *(const float4*)(xp1 + kb * 32 + 4);
            xv1[0] = c.x; xv1[1] = c.y; xv1[2] = c.z; xv1[3] = c.w;
            xv1[4] = d.x; xv1[5] = d.y; xv1[6] = d.z; xv1[7] = d.w;
        } else {
#pragma unroll
            for (int j = 0; j < 8; ++j) {
                int kk = kb * 32 + q * 8 + j;
                xv0[j] = (kk < F_IN) ? xp0[kb * 32 + j] : 0.f;
                xv1[j] = (kk < F_IN) ? xp1[kb * 32 + j] : 0.f;
            }
        }
        bf16x8 xh0, xl0, xh1, xl1;
#pragma unroll
        for (int j = 0; j < 8; ++j) {
            unsigned int b0 = __float_as_uint(xv0[j]);
            xh0[j] = (short)(b0 >> 16);
            float res0 = xv0[j] - __uint_as_float(b0 & 0xffff0000u);
            xl0[j] = (short)(__float_as_uint(res0) >> 16);
            unsigned int b1 = __float_as_uint(xv1[j]);
            xh1[j] = (short)(b1 >> 16);
            float res1 = xv1[j] - __uint_as_float(b1 & 0xffff0000u);
            xl1[j] = (short)(__float_as_uint(res1) >> 16);
        }
#pragma unroll
        for (int fb = 0; fb < 4; ++fb) {
            bf16x8 bh = whv[(size_t)(kb * 4 + fb) * 64 + lane];
            bf16x8 bl = wlv[(size_t)(kb * 4 + fb) * 64 + lane];
            acc[0][fb] = __builtin_amdgcn_mfma_f32_16x16x32_bf16(xh0, bh, acc[0][fb], 0, 0, 0);
            acc[0][fb] = __builtin_amdgcn_mfma_f32_16x16x32_bf16(xl0, bh, acc[0][fb], 0, 0, 0);
            acc[0][fb] = __builtin_amdgcn_mfma_f32_16x16x32_bf16(xh0, bl, acc[0][fb], 0, 0, 0);
            acc[1][fb] = __builtin_amdgcn_mfma_f32_16x16x32_bf16(xh1, bh, acc[1][fb], 0, 0, 0);
            acc[1][fb] = __builtin_amdgcn_mfma_f32_16x16x32_bf16(xl1, bh, acc[1][fb], 0, 0, 0);
            acc[1][fb] = __builtin_amdgcn_mfma_f32_16x16x32_bf16(xh1, bl, acc[1][fb], 0, 0, 0);
        }
    }
#pragma unroll
    for (int t = 0; t < 2; ++t) {
#pragma unroll
        for (int r = 0; r < 4; ++r) {
            int node = n0 + t * 16 + q * 4 + r;
            if (node < N) {
                float dn = dis[node];
#pragma unroll
                for (int fb = 0; fb < 4; ++fb) {
                    h1b[(size_t)node * HDIM + fb * 16 + fl] =
                        f2bf(acc[t][fb][r] * dn);
                }
            }
        }
    }
}

// ---------------------------------------------------------------------------
// Stage 5 (FUSED gather1 + layer2): wave per node (grid-stride).
// lane = g*16+c: group g in [0,4) walks edges beg+g stride 4; feat quad
// 4c..4c+3 as one 8-B load.  Cross-group shfl reduce; then relu+bias and the
// 64x10 MLP in-register (W2 rows held per-lane, loaded once per wave);
// butterfly reduce over c; store h2s[node] = (t@W2)*dis[node], stride 16.
// ---------------------------------------------------------------------------
__global__ __launch_bounds__(256) void gather1_mlp_kernel(
        const int* __restrict__ row_ptr, const int* __restrict__ blk_sum,
        const int* __restrict__ csr_src, const float* __restrict__ dis,
        const unsigned short* __restrict__ h1b,
        const float* __restrict__ b1, const float* __restrict__ W2,
        float* __restrict__ h2s, int N) {
    const int lane = threadIdx.x & 63;
    const int g = lane >> 4;
    const int c = lane & 15;
    const int gw = (blockIdx.x * 256 + threadIdx.x) >> 6;
    const int nwaves = (gridDim.x * 256) >> 6;

    // per-lane constants: W2 rows 4c..4c+3, bias quad
    float w2r[4][CDIM];
#pragma unroll
    for (int i = 0; i < 4; ++i)
#pragma unroll
        for (int j = 0; j < CDIM; ++j) w2r[i][j] = W2[(4 * c + i) * CDIM + j];
    float4 b1q = *(const float4*)(b1 + 4 * c);
    float b1r[4] = {b1q.x, b1q.y, b1q.z, b1q.w};

    for (int nid = gw; nid < N; nid += nwaves) {
        int node = __builtin_amdgcn_readfirstlane(nid);
        int beg = row_ptr[node] + blk_sum[node >> 10];
        int end = row_ptr[node + 1] + blk_sum[(node + 1) >> 10];
        float dd = dis[node];
        float a0 = 0.f, a1 = 0.f, a2 = 0.f, a3 = 0.f;
        if (g == 0) {  // self-loop (row already scaled by dis[node])
            uint2 w = *(const uint2*)(h1b + (size_t)node * HDIM + 4 * c);
            a0 = bflo(w.x); a1 = bfhi(w.x); a2 = bflo(w.y); a3 = bfhi(w.y);
        }
        int p = beg + g;
        for (; p + 12 < end; p += 16) {  // 4 edges in flight per group
            int s0 = csr_src[p];
            int s1 = csr_src[p + 4];
            int s2 = csr_src[p + 8];
            int s3 = csr_src[p + 12];
            uint2 w0 = *(const uint2*)(h1b + (size_t)s0 * HDIM + 4 * c);
            uint2 w1 = *(const uint2*)(h1b + (size_t)s1 * HDIM + 4 * c);
            uint2 w2 = *(const uint2*)(h1b + (size_t)s2 * HDIM + 4 * c);
            uint2 w3 = *(const uint2*)(h1b + (size_t)s3 * HDIM + 4 * c);
            a0 += bflo(w0.x); a1 += bfhi(w0.x); a2 += bflo(w0.y); a3 += bfhi(w0.y);
            a0 += bflo(w1.x); a1 += bfhi(w1.x); a2 += bflo(w1.y); a3 += bfhi(w1.y);
            a0 += bflo(w2.x); a1 += bfhi(w2.x); a2 += bflo(w2.y); a3 += bfhi(w2.y);
            a0 += bflo(w3.x); a1 += bfhi(w3.x); a2 += bflo(w3.y); a3 += bfhi(w3.y);
        }
        for (; p < end; p += 4) {
            int s0 = csr_src[p];
            uint2 w0 = *(const uint2*)(h1b + (size_t)s0 * HDIM + 4 * c);
            a0 += bflo(w0.x); a1 += bfhi(w0.x); a2 += bflo(w0.y); a3 += bfhi(w0.y);
        }
        // reduce across the 4 groups (lanes with same c)
        a0 += __shfl_xor(a0, 16); a0 += __shfl_xor(a0, 32);
        a1 += __shfl_xor(a1, 16); a1 += __shfl_xor(a1, 32);
        a2 += __shfl_xor(a2, 16); a2 += __shfl_xor(a2, 32);
        a3 += __shfl_xor(a3, 16); a3 += __shfl_xor(a3, 32);
        // relu(agg*dd + b1) then MLP partial over this lane's 4 features
        float t0 = fmaf(a0, dd, b1r[0]); t0 = t0 > 0.f ? t0 : 0.f;
        float t1 = fmaf(a1, dd, b1r[1]); t1 = t1 > 0.f ? t1 : 0.f;
        float t2 = fmaf(a2, dd, b1r[2]); t2 = t2 > 0.f ? t2 : 0.f;
        float t3 = fmaf(a3, dd, b1r[3]); t3 = t3 > 0.f ? t3 : 0.f;
        float pj[CDIM];
#pragma unroll
        for (int j = 0; j < CDIM; ++j)
            pj[j] = fmaf(t0, w2r[0][j],
                    fmaf(t1, w2r[1][j],
                    fmaf(t2, w2r[2][j], t3 * w2r[3][j])));
        // butterfly over c (bits 0..3) — every lane ends with full sums
#pragma unroll
        for (int off = 1; off < 16; off <<= 1)
#pragma unroll
            for (int j = 0; j < CDIM; ++j) pj[j] += __shfl_xor(pj[j], off);
        // lane j (< CDIM) stores element j
        float v = pj[0];
#pragma unroll
        for (int j = 1; j < CDIM; ++j) v = (lane == j) ? pj[j] : v;
        if (lane < CDIM) h2s[(size_t)node * H2LD + lane] = v * dd;
    }
}

// ---------------------------------------------------------------------------
// Stage 6: gather layer 2.  Wave per node (grid-stride), 4 groups x 16 lanes,
// h2s rows padded to 64 B; shfl reduce; bias + self term at the end.
// ---------------------------------------------------------------------------
__global__ __launch_bounds__(256) void gather2_kernel(
        const int* __restrict__ row_ptr, const int* __restrict__ blk_sum,
        const int* __restrict__ csr_src, const float* __restrict__ dis,
        const float* __restrict__ h2s, const float* __restrict__ b2,
        float* __restrict__ out, int N) {
    const int lane = threadIdx.x & 63;
    const int g = lane >> 4;
    const int j = lane & 15;
    const int gw = (blockIdx.x * 256 + threadIdx.x) >> 6;
    const int nwaves = (gridDim.x * 256) >> 6;

    for (int nid = gw; nid < N; nid += nwaves) {
        int node = __builtin_amdgcn_readfirstlane(nid);
        int beg = row_ptr[node] + blk_sum[node >> 10];
        int end = row_ptr[node + 1] + blk_sum[(node + 1) >> 10];
        float acc = 0.f;
        int p = beg + g;
        for (; p + 4 < end; p += 8) {  // 2 edges in flight per group
            int s0 = csr_src[p];
            int s1 = csr_src[p + 4];
            float v0 = (j < CDIM) ? h2s[(size_t)s0 * H2LD + j] : 0.f;
            float v1 = (j < CDIM) ? h2s[(size_t)s1 * H2LD + j] : 0.f;
            acc += v0 + v1;
        }
        for (; p < end; p += 4) {
            int s0 = csr_src[p];
            acc += (j < CDIM) ? h2s[(size_t)s0 * H2LD + j] : 0.f;
        }
        acc += __shfl_xor(acc, 16);
        acc += __shfl_xor(acc, 32);
        if (lane < CDIM) {
            float dd = dis[node];
            out[(size_t)node * CDIM + lane] =
                b2[lane] + dd * (acc + h2s[(size_t)node * H2LD + lane]);
        }
    }
}

// ---------------------------------------------------------------------------
static inline char* align256(char* p) {
    return (char*)(((uintptr_t)p + 255) & ~(uintptr_t)255);
}

extern "C" void kernel_launch(void* const* d_in, const int* in_sizes, int n_in,
                              void* d_out, int out_size, void* d_ws,
                              size_t ws_size, hipStream_t stream) {
    const float* x  = (const float*)d_in[0];
    const int*   ei = (const int*)d_in[1];
    const float* W1 = (const float*)d_in[2];
    const float* b1 = (const float*)d_in[3];
    const float* W2 = (const float*)d_in[4];
    const float* b2 = (const float*)d_in[5];

    const int N = in_sizes[0] / F_IN;   // 100000
    const int E = in_sizes[1] / 2;      // 1600000
    const int* src = ei;
    const int* dst = ei + E;
    float* out = (float*)d_out;

    const int Np1 = N + 1;
    const int nscan_blocks = (Np1 + 1023) / 1024;

    // workspace layout (~28 MB), 256B-aligned chunks
    char* w = (char*)d_ws;
    int* deg = (int*)w;                  w = align256(w + (size_t)N * 4);  // zeroed
    int* cursor = (int*)w;               w = align256(w + (size_t)N * 4);  // zeroed
    char* zero_end = w;
    float* dis = (float*)w;              w = align256(w + (size_t)N * 4);
    int* row_ptr = (int*)w;              w = align256(w + (size_t)(N + 4) * 4);
    int* blk_sum = (int*)w;              w = align256(w + (size_t)nscan_blocks * 4);
    int* csr_src = (int*)w;              w = align256(w + (size_t)E * 4);
    unsigned short* whf = (unsigned short*)w;  w = align256(w + (size_t)KPAD * HDIM * 2);
    unsigned short* wlf = (unsigned short*)w;  w = align256(w + (size_t)KPAD * HDIM * 2);
    unsigned short* h1b = (unsigned short*)w;  w = align256(w + (size_t)N * HDIM * 2);
    float* h2s = (float*)w;              w = align256(w + (size_t)N * H2LD * 4);

    hipMemsetAsync(deg, 0, (size_t)(zero_end - (char*)deg), stream);  // deg+cursor

    wprep_kernel<<<(KPAD * HDIM + 255) / 256, 256, 0, stream>>>(W1, whf, wlf);
    deg_count_kernel<<<(E + 255) / 256, 256, 0, stream>>>(dst, E, deg);
    scan_block_kernel<<<nscan_blocks, 1024, 0, stream>>>(deg, row_ptr, blk_sum,
                                                         dis, Np1);
    scan_top_kernel<<<1, 64, 0, stream>>>(blk_sum, nscan_blocks);
    csr_fill_kernel<<<(E + 255) / 256, 256, 0, stream>>>(src, dst, row_ptr,
                                                         blk_sum, cursor,
                                                         csr_src, E);
    {
        int nwaves = (N + 31) / 32;
        int blocks = (nwaves + 3) / 4;
        gemm1_kernel<<<blocks, 256, 0, stream>>>(x, whf, wlf, dis, h1b, N);
    }
    gather1_mlp_kernel<<<2048, 256, 0, stream>>>(row_ptr, blk_sum, csr_src,
                                                 dis, h1b, b1, W2, h2s, N);
    gather2_kernel<<<2048, 256, 0, stream>>>(row_ptr, blk_sum, csr_src, dis,
                                             h2s, b2, out, N);
}

// Round 7
// 563.240 us; speedup vs baseline: 1.0577x; 1.0577x over previous
//
#include <hip/hip_runtime.h>

#define F_IN 500
#define HDIM 64
#define CDIM 10
#define KPAD 512           // K padded to 16 MFMA stages of 32
#define NSTAGE 16
#define H2LD 16            // padded h2s row stride (64 B lines)

typedef __attribute__((ext_vector_type(8))) short bf16x8;
typedef __attribute__((ext_vector_type(4))) float floatx4;

// RNE fp32 -> bf16 bits
__device__ inline unsigned short f2bf(float f) {
    unsigned int u = __float_as_uint(f);
    u += 0x7fffu + ((u >> 16) & 1u);
    return (unsigned short)(u >> 16);
}
__device__ inline float bflo(unsigned int u) { return __uint_as_float(u << 16); }
__device__ inline float bfhi(unsigned int u) { return __uint_as_float(u & 0xffff0000u); }

// ---------------------------------------------------------------------------
// Fused Stage 1: blocks [0, degB) do in-degree histogram; blocks [degB, ..)
// split W1 into truncated-bf16 hi + bf16 residual in MFMA B-fragment order.
// ---------------------------------------------------------------------------
__global__ __launch_bounds__(256) void prep_kernel(
        const int* __restrict__ dst, int E, int* __restrict__ deg,
        const float* __restrict__ W1, unsigned short* __restrict__ whf,
        unsigned short* __restrict__ wlf, int degB) {
    int bid = blockIdx.x;
    if (bid < degB) {
        int e = bid * 256 + threadIdx.x;
        if (e < E) atomicAdd(&deg[dst[e]], 1);
    } else {
        int idx = (bid - degB) * 256 + threadIdx.x;  // over KPAD*HDIM
        if (idx >= KPAD * HDIM) return;
        int k = idx >> 6;
        int f = idx & 63;
        float w = (k < F_IN) ? W1[k * HDIM + f] : 0.f;
        unsigned int b = __float_as_uint(w);
        unsigned short hh = (unsigned short)(b >> 16);
        float wl = w - __uint_as_float(b & 0xffff0000u);
        unsigned short ll = (unsigned short)(__float_as_uint(wl) >> 16);
        int kb = k >> 5, q = (k >> 3) & 3, j = k & 7;
        int fb = f >> 4, fl = f & 15;
        int lane = (q << 4) | fl;
        size_t o = ((((size_t)kb * 4 + fb) * 64 + lane) << 3) | (size_t)j;
        whf[o] = hh;
        wlf[o] = ll;
    }
}

// ---------------------------------------------------------------------------
// Stage 2: per-block exclusive scan deg -> row_ptr partials; dis fused.
// Final row base = row_ptr[i] + blk_sum[i>>10]; consumers do the add.
// ---------------------------------------------------------------------------
__global__ void scan_block_kernel(const int* __restrict__ deg,
                                  int* __restrict__ row_ptr,
                                  int* __restrict__ blk_sum,
                                  float* __restrict__ dis, int Np1) {
    __shared__ int wsum[16];
    int i = blockIdx.x * 1024 + threadIdx.x;
    int v = (i < Np1 - 1) ? deg[i] : 0;
    if (i < Np1 - 1) dis[i] = rsqrtf((float)(v + 1));
    int lane = threadIdx.x & 63;
    int wid = threadIdx.x >> 6;
    int x = v;
#pragma unroll
    for (int off = 1; off < 64; off <<= 1) {
        int y = __shfl_up(x, off);
        if (lane >= off) x += y;
    }
    if (lane == 63) wsum[wid] = x;
    __syncthreads();
    if (threadIdx.x < 16) {
        int ws = wsum[threadIdx.x];
#pragma unroll
        for (int off = 1; off < 16; off <<= 1) {
            int y = __shfl_up(ws, off);
            if ((int)threadIdx.x >= off) ws += y;
        }
        wsum[threadIdx.x] = ws;
    }
    __syncthreads();
    int wp = (wid > 0) ? wsum[wid - 1] : 0;
    if (i < Np1) row_ptr[i] = wp + x - v;
    if (threadIdx.x == 1023) blk_sum[blockIdx.x] = wp + x;
}

__global__ void scan_top_kernel(int* __restrict__ blk_sum, int nb) {
    int carry = 0;
    for (int base = 0; base < nb; base += 64) {
        int i = base + (int)threadIdx.x;
        int v = (i < nb) ? blk_sum[i] : 0;
        int x = v;
#pragma unroll
        for (int off = 1; off < 64; off <<= 1) {
            int y = __shfl_up(x, off);
            if ((int)threadIdx.x >= off) x += y;
        }
        if (i < nb) blk_sum[i] = carry + x - v;
        carry += __shfl(x, 63);
    }
}

// ---------------------------------------------------------------------------
// Fused Stage 3+4: blocks [0, gemmB) run the MFMA GEMM (h1b = bf16(x@W1 *
// dis)); blocks [gemmB, ..) run the CSR fill.  The two are independent and
// overlap in one dispatch.
// ---------------------------------------------------------------------------
__global__ __launch_bounds__(256) void csr_gemm_kernel(
        // gemm args
        const float* __restrict__ x, const unsigned short* __restrict__ whf,
        const unsigned short* __restrict__ wlf, const float* __restrict__ dis,
        unsigned short* __restrict__ h1b, int N,
        // csr args
        const int* __restrict__ src, const int* __restrict__ dst,
        const int* __restrict__ row_ptr, const int* __restrict__ blk_sum,
        int* __restrict__ cursor, int* __restrict__ csr_src, int E,
        int gemmB) {
    const int bid = blockIdx.x;
    if (bid >= gemmB) {
        // ----- CSR fill path -----
        int e = (bid - gemmB) * 256 + threadIdx.x;
        if (e >= E) return;
        int d = dst[e];
        int pos = atomicAdd(&cursor[d], 1);
        csr_src[row_ptr[d] + blk_sum[d >> 10] + pos] = src[e];
        return;
    }
    // ----- GEMM path -----
    const int lane = threadIdx.x & 63;
    const int wid = (bid * 256 + threadIdx.x) >> 6;
    const int n0 = wid * 32;
    if (n0 >= N) return;
    const int q = lane >> 4;
    const int fl = lane & 15;

    int r0 = n0 + fl;       if (r0 >= N) r0 = N - 1;
    int r1 = n0 + 16 + fl;  if (r1 >= N) r1 = N - 1;
    const float* xp0 = x + (size_t)r0 * F_IN + q * 8;
    const float* xp1 = x + (size_t)r1 * F_IN + q * 8;

    floatx4 acc[2][4];
#pragma unroll
    for (int t = 0; t < 2; ++t)
#pragma unroll
        for (int fb = 0; fb < 4; ++fb) acc[t][fb] = (floatx4){0.f, 0.f, 0.f, 0.f};

    const bf16x8* whv = (const bf16x8*)whf;
    const bf16x8* wlv = (const bf16x8*)wlf;

    for (int kb = 0; kb < NSTAGE; ++kb) {
        float xv0[8], xv1[8];
        if (kb < NSTAGE - 1) {
            float4 a = *(const float4*)(xp0 + kb * 32);
            float4 b = *(const float4*)(xp0 + kb * 32 + 4);
            xv0[0] = a.x; xv0[1] = a.y; xv0[2] = a.z; xv0[3] = a.w;
            xv0[4] = b.x; xv0[5] = b.y; xv0[6] = b.z; xv0[7] = b.w;
            float4 c = *(const float4*)(xp1 + kb * 32);
            float4 d = *(const float4*)(xp1 + kb * 32 + 4);
            xv1[0] = c.x; xv1[1] = c.y; xv1[2] = c.z; xv1[3] = c.w;
            xv1[4] = d.x; xv1[5] = d.y; xv1[6] = d.z; xv1[7] = d.w;
        } else {
#pragma unroll
            for (int j = 0; j < 8; ++j) {
                int kk = kb * 32 + q * 8 + j;
                xv0[j] = (kk < F_IN) ? xp0[kb * 32 + j] : 0.f;
                xv1[j] = (kk < F_IN) ? xp1[kb * 32 + j] : 0.f;
            }
        }
        bf16x8 xh0, xl0, xh1, xl1;
#pragma unroll
        for (int j = 0; j < 8; ++j) {
            unsigned int b0 = __float_as_uint(xv0[j]);
            xh0[j] = (short)(b0 >> 16);
            float res0 = xv0[j] - __uint_as_float(b0 & 0xffff0000u);
            xl0[j] = (short)(__float_as_uint(res0) >> 16);
            unsigned int b1 = __float_as_uint(xv1[j]);
            xh1[j] = (short)(b1 >> 16);
            float res1 = xv1[j] - __uint_as_float(b1 & 0xffff0000u);
            xl1[j] = (short)(__float_as_uint(res1) >> 16);
        }
#pragma unroll
        for (int fb = 0; fb < 4; ++fb) {
            bf16x8 bh = whv[(size_t)(kb * 4 + fb) * 64 + lane];
            bf16x8 bl = wlv[(size_t)(kb * 4 + fb) * 64 + lane];
            acc[0][fb] = __builtin_amdgcn_mfma_f32_16x16x32_bf16(xh0, bh, acc[0][fb], 0, 0, 0);
            acc[0][fb] = __builtin_amdgcn_mfma_f32_16x16x32_bf16(xl0, bh, acc[0][fb], 0, 0, 0);
            acc[0][fb] = __builtin_amdgcn_mfma_f32_16x16x32_bf16(xh0, bl, acc[0][fb], 0, 0, 0);
            acc[1][fb] = __builtin_amdgcn_mfma_f32_16x16x32_bf16(xh1, bh, acc[1][fb], 0, 0, 0);
            acc[1][fb] = __builtin_amdgcn_mfma_f32_16x16x32_bf16(xl1, bh, acc[1][fb], 0, 0, 0);
            acc[1][fb] = __builtin_amdgcn_mfma_f32_16x16x32_bf16(xh1, bl, acc[1][fb], 0, 0, 0);
        }
    }
#pragma unroll
    for (int t = 0; t < 2; ++t) {
#pragma unroll
        for (int r = 0; r < 4; ++r) {
            int node = n0 + t * 16 + q * 4 + r;
            if (node < N) {
                float dn = dis[node];
#pragma unroll
                for (int fb = 0; fb < 4; ++fb) {
                    h1b[(size_t)node * HDIM + fb * 16 + fl] =
                        f2bf(acc[t][fb][r] * dn);
                }
            }
        }
    }
}

// ---------------------------------------------------------------------------
// Stage 5: gather layer 1.  h1b rows pre-scaled by dis[s] -> pure adds.
// Wave per node, half-wave per edge parity, 8 edges in flight per half.
// ---------------------------------------------------------------------------
__global__ __launch_bounds__(256) void gather1_kernel(
        const int* __restrict__ row_ptr, const int* __restrict__ blk_sum,
        const int* __restrict__ csr_src, const float* __restrict__ dis,
        const unsigned short* __restrict__ h1b,
        float* __restrict__ agg1, int N) {
    int nid = blockIdx.x * 4 + (threadIdx.x >> 6);
    if (nid >= N) return;
    int node = __builtin_amdgcn_readfirstlane(nid);
    int lane = threadIdx.x & 63;
    int half = lane >> 5;
    int c = lane & 31;  // features 2c, 2c+1
    int beg = row_ptr[node] + blk_sum[node >> 10];
    int end = row_ptr[node + 1] + blk_sum[(node + 1) >> 10];
    float dd = dis[node];
    float a0 = 0.f, a1 = 0.f;
    if (half == 0) {  // self-loop: row already holds h1*dis[node]
        unsigned int w = *reinterpret_cast<const unsigned int*>(
            h1b + (size_t)node * HDIM + 2 * c);
        a0 = bflo(w);
        a1 = bfhi(w);
    }
    int p = beg + half;
    for (; p + 14 < end; p += 16) {  // 8 edges in flight per half
        unsigned int wv[8];
#pragma unroll
        for (int i = 0; i < 8; ++i) {
            int s = csr_src[p + 2 * i];
            wv[i] = *reinterpret_cast<const unsigned int*>(
                h1b + (size_t)s * HDIM + 2 * c);
        }
#pragma unroll
        for (int i = 0; i < 8; ++i) {
            a0 += bflo(wv[i]);
            a1 += bfhi(wv[i]);
        }
    }
    for (; p < end; p += 2) {
        int s0 = csr_src[p];
        unsigned int w0 = *reinterpret_cast<const unsigned int*>(
            h1b + (size_t)s0 * HDIM + 2 * c);
        a0 += bflo(w0);
        a1 += bfhi(w0);
    }
    a0 += __shfl_xor(a0, 32);
    a1 += __shfl_xor(a1, 32);
    if (half == 0) {
        *reinterpret_cast<float2*>(agg1 + (size_t)node * HDIM + 2 * c) =
            make_float2(a0 * dd, a1 * dd);
    }
}

// ---------------------------------------------------------------------------
// Stage 6: layer 2 dense: t = relu(agg1+b1); h2s[n] = (t @ W2) * dis[n],
// row stride 16 (pad never read downstream).
// ---------------------------------------------------------------------------
__global__ void layer2_kernel(const float* __restrict__ agg1,
                              const float* __restrict__ b1,
                              const float* __restrict__ W2,
                              const float* __restrict__ dis,
                              float* __restrict__ h2s, int N) {
    int n = blockIdx.x * blockDim.x + threadIdx.x;
    if (n >= N) return;
    const float* ar = agg1 + (size_t)n * HDIM;
    float t[HDIM];
#pragma unroll
    for (int c = 0; c < HDIM; ++c) {
        float v = ar[c] + b1[c];
        t[c] = v > 0.f ? v : 0.f;
    }
    float dn = dis[n];
    float* h2r = h2s + (size_t)n * H2LD;
#pragma unroll
    for (int j = 0; j < CDIM; ++j) {
        float acc = 0.f;
#pragma unroll
        for (int c = 0; c < HDIM; ++c) acc = fmaf(t[c], W2[c * CDIM + j], acc);
        h2r[j] = acc * dn;
    }
}

// ---------------------------------------------------------------------------
// Stage 7: gather layer 2.  Wave per node, 4 groups x 16 lanes, 4 edges in
// flight per group; h2s rows 64-B aligned; shfl reduce; bias + self at end.
// ---------------------------------------------------------------------------
__global__ __launch_bounds__(256) void gather2_kernel(
        const int* __restrict__ row_ptr, const int* __restrict__ blk_sum,
        const int* __restrict__ csr_src, const float* __restrict__ dis,
        const float* __restrict__ h2s, const float* __restrict__ b2,
        float* __restrict__ out, int N) {
    int nid = blockIdx.x * 4 + (threadIdx.x >> 6);
    if (nid >= N) return;
    int node = __builtin_amdgcn_readfirstlane(nid);
    int lane = threadIdx.x & 63;
    int g = lane >> 4;
    int j = lane & 15;
    int beg = row_ptr[node] + blk_sum[node >> 10];
    int end = row_ptr[node + 1] + blk_sum[(node + 1) >> 10];
    float acc = 0.f;
    int p = beg + g;
    for (; p + 12 < end; p += 16) {  // 4 edges in flight per group
        int s0 = csr_src[p];
        int s1 = csr_src[p + 4];
        int s2 = csr_src[p + 8];
        int s3 = csr_src[p + 12];
        float v0 = (j < CDIM) ? h2s[(size_t)s0 * H2LD + j] : 0.f;
        float v1 = (j < CDIM) ? h2s[(size_t)s1 * H2LD + j] : 0.f;
        float v2 = (j < CDIM) ? h2s[(size_t)s2 * H2LD + j] : 0.f;
        float v3 = (j < CDIM) ? h2s[(size_t)s3 * H2LD + j] : 0.f;
        acc += (v0 + v1) + (v2 + v3);
    }
    for (; p < end; p += 4) {
        int s0 = csr_src[p];
        acc += (j < CDIM) ? h2s[(size_t)s0 * H2LD + j] : 0.f;
    }
    acc += __shfl_xor(acc, 16);
    acc += __shfl_xor(acc, 32);
    if (lane < CDIM) {
        float dd = dis[node];
        out[(size_t)node * CDIM + lane] =
            b2[lane] + dd * (acc + h2s[(size_t)node * H2LD + lane]);
    }
}

// ---------------------------------------------------------------------------
static inline char* align256(char* p) {
    return (char*)(((uintptr_t)p + 255) & ~(uintptr_t)255);
}

extern "C" void kernel_launch(void* const* d_in, const int* in_sizes, int n_in,
                              void* d_out, int out_size, void* d_ws,
                              size_t ws_size, hipStream_t stream) {
    const float* x  = (const float*)d_in[0];
    const int*   ei = (const int*)d_in[1];
    const float* W1 = (const float*)d_in[2];
    const float* b1 = (const float*)d_in[3];
    const float* W2 = (const float*)d_in[4];
    const float* b2 = (const float*)d_in[5];

    const int N = in_sizes[0] / F_IN;   // 100000
    const int E = in_sizes[1] / 2;      // 1600000
    const int* src = ei;
    const int* dst = ei + E;
    float* out = (float*)d_out;

    const int Np1 = N + 1;
    const int nscan_blocks = (Np1 + 1023) / 1024;

    // workspace layout (~32 MB), 256B-aligned chunks
    char* w = (char*)d_ws;
    int* deg = (int*)w;                  w = align256(w + (size_t)N * 4);  // zeroed
    int* cursor = (int*)w;               w = align256(w + (size_t)N * 4);  // zeroed
    char* zero_end = w;
    float* dis = (float*)w;              w = align256(w + (size_t)N * 4);
    int* row_ptr = (int*)w;              w = align256(w + (size_t)(N + 4) * 4);
    int* blk_sum = (int*)w;              w = align256(w + (size_t)nscan_blocks * 4);
    int* csr_src = (int*)w;              w = align256(w + (size_t)E * 4);
    unsigned short* whf = (unsigned short*)w;  w = align256(w + (size_t)KPAD * HDIM * 2);
    unsigned short* wlf = (unsigned short*)w;  w = align256(w + (size_t)KPAD * HDIM * 2);
    unsigned short* h1b = (unsigned short*)w;  w = align256(w + (size_t)N * HDIM * 2);
    float* agg1 = (float*)w;             w = align256(w + (size_t)N * HDIM * 4);
    float* h2s = (float*)w;              w = align256(w + (size_t)N * H2LD * 4);

    hipMemsetAsync(deg, 0, (size_t)(zero_end - (char*)deg), stream);  // deg+cursor

    const int degB = (E + 255) / 256;                    // 6250
    const int wprepB = (KPAD * HDIM + 255) / 256;        // 128
    prep_kernel<<<degB + wprepB, 256, 0, stream>>>(dst, E, deg, W1, whf, wlf,
                                                   degB);
    scan_block_kernel<<<nscan_blocks, 1024, 0, stream>>>(deg, row_ptr, blk_sum,
                                                         dis, Np1);
    scan_top_kernel<<<1, 64, 0, stream>>>(blk_sum, nscan_blocks);
    {
        int gemmB = ((N + 31) / 32 + 3) / 4;             // 782
        int csrB = (E + 255) / 256;                      // 6250
        csr_gemm_kernel<<<gemmB + csrB, 256, 0, stream>>>(
            x, whf, wlf, dis, h1b, N,
            src, dst, row_ptr, blk_sum, cursor, csr_src, E, gemmB);
    }
    gather1_kernel<<<(N + 3) / 4, 256, 0, stream>>>(row_ptr, blk_sum, csr_src,
                                                    dis, h1b, agg1, N);
    layer2_kernel<<<(N + 255) / 256, 256, 0, stream>>>(agg1, b1, W2, dis, h2s,
                                                       N);
    gather2_kernel<<<(N + 3) / 4, 256, 0, stream>>>(row_ptr, blk_sum, csr_src,
                                                    dis, h2s, b2, out, N);
}

// Round 8
// 543.180 us; speedup vs baseline: 1.0968x; 1.0369x over previous
//
#include <hip/hip_runtime.h>

#define F_IN 500
#define HDIM 64
#define CDIM 10
#define KPAD 512           // K padded to 16 MFMA stages of 32
#define NSTAGE 16
#define H2LD 16            // padded h2s row stride (64 B lines)

typedef __attribute__((ext_vector_type(8))) short bf16x8;
typedef __attribute__((ext_vector_type(4))) float floatx4;

// RNE fp32 -> bf16 bits
__device__ inline unsigned short f2bf(float f) {
    unsigned int u = __float_as_uint(f);
    u += 0x7fffu + ((u >> 16) & 1u);
    return (unsigned short)(u >> 16);
}
__device__ inline float bflo(unsigned int u) { return __uint_as_float(u << 16); }
__device__ inline float bfhi(unsigned int u) { return __uint_as_float(u & 0xffff0000u); }

// ---------------------------------------------------------------------------
// Fused Stage 1: blocks [0, degB): in-degree histogram; the returned old
// value IS the edge's rank within its dst row -> erank (kills the cursor
// atomics later).  Blocks [degB, ..): W1 split into trunc-bf16 hi + residual
// in MFMA B-fragment order.
// ---------------------------------------------------------------------------
__global__ __launch_bounds__(256) void prep_kernel(
        const int* __restrict__ dst, int E, int* __restrict__ deg,
        int* __restrict__ erank,
        const float* __restrict__ W1, unsigned short* __restrict__ whf,
        unsigned short* __restrict__ wlf, int degB) {
    int bid = blockIdx.x;
    if (bid < degB) {
        int e = bid * 256 + threadIdx.x;
        if (e < E) erank[e] = atomicAdd(&deg[dst[e]], 1);
    } else {
        int idx = (bid - degB) * 256 + threadIdx.x;  // over KPAD*HDIM
        if (idx >= KPAD * HDIM) return;
        int k = idx >> 6;
        int f = idx & 63;
        float w = (k < F_IN) ? W1[k * HDIM + f] : 0.f;
        unsigned int b = __float_as_uint(w);
        unsigned short hh = (unsigned short)(b >> 16);
        float wl = w - __uint_as_float(b & 0xffff0000u);
        unsigned short ll = (unsigned short)(__float_as_uint(wl) >> 16);
        int kb = k >> 5, q = (k >> 3) & 3, j = k & 7;
        int fb = f >> 4, fl = f & 15;
        int lane = (q << 4) | fl;
        size_t o = ((((size_t)kb * 4 + fb) * 64 + lane) << 3) | (size_t)j;
        whf[o] = hh;
        wlf[o] = ll;
    }
}

// ---------------------------------------------------------------------------
// Stage 2: per-block exclusive scan deg -> row_ptr partials; dis fused.
// Final row base = row_ptr[i] + blk_sum[i>>10]; consumers do the add.
// ---------------------------------------------------------------------------
__global__ void scan_block_kernel(const int* __restrict__ deg,
                                  int* __restrict__ row_ptr,
                                  int* __restrict__ blk_sum,
                                  float* __restrict__ dis, int Np1) {
    __shared__ int wsum[16];
    int i = blockIdx.x * 1024 + threadIdx.x;
    int v = (i < Np1 - 1) ? deg[i] : 0;
    if (i < Np1 - 1) dis[i] = rsqrtf((float)(v + 1));
    int lane = threadIdx.x & 63;
    int wid = threadIdx.x >> 6;
    int x = v;
#pragma unroll
    for (int off = 1; off < 64; off <<= 1) {
        int y = __shfl_up(x, off);
        if (lane >= off) x += y;
    }
    if (lane == 63) wsum[wid] = x;
    __syncthreads();
    if (threadIdx.x < 16) {
        int ws = wsum[threadIdx.x];
#pragma unroll
        for (int off = 1; off < 16; off <<= 1) {
            int y = __shfl_up(ws, off);
            if ((int)threadIdx.x >= off) ws += y;
        }
        wsum[threadIdx.x] = ws;
    }
    __syncthreads();
    int wp = (wid > 0) ? wsum[wid - 1] : 0;
    if (i < Np1) row_ptr[i] = wp + x - v;
    if (threadIdx.x == 1023) blk_sum[blockIdx.x] = wp + x;
}

__global__ void scan_top_kernel(int* __restrict__ blk_sum, int nb) {
    int carry = 0;
    for (int base = 0; base < nb; base += 64) {
        int i = base + (int)threadIdx.x;
        int v = (i < nb) ? blk_sum[i] : 0;
        int x = v;
#pragma unroll
        for (int off = 1; off < 64; off <<= 1) {
            int y = __shfl_up(x, off);
            if ((int)threadIdx.x >= off) x += y;
        }
        if (i < nb) blk_sum[i] = carry + x - v;
        carry += __shfl(x, 63);
    }
}

// ---------------------------------------------------------------------------
// Fused Stage 3+4, INTERLEAVED: every 9th block (bid%9==0, first gemmB such)
// runs the MFMA GEMM; all others run the atomic-free CSR scatter.  The blend
// keeps each CU's MFMA pipe and memory pipe busy simultaneously.
// GEMM K-loop is depth-2 software-pipelined (prefetch x for kb+1).
// ---------------------------------------------------------------------------
__global__ __launch_bounds__(256) void csr_gemm_kernel(
        // gemm args
        const float* __restrict__ x, const unsigned short* __restrict__ whf,
        const unsigned short* __restrict__ wlf, const float* __restrict__ dis,
        unsigned short* __restrict__ h1b, int N,
        // csr args
        const int* __restrict__ src, const int* __restrict__ dst,
        const int* __restrict__ erank,
        const int* __restrict__ row_ptr, const int* __restrict__ blk_sum,
        int* __restrict__ csr_src, int E,
        int gemmB) {
    const int bid = blockIdx.x;
    const int g9 = bid / 9;
    const bool isGemm = (bid % 9 == 0) && (g9 < gemmB);
    if (!isGemm) {
        // ----- CSR fill path (no atomics: rank precomputed in prep) -----
        int before = (bid + 8) / 9;          // gemm blocks preceding bid
        if (before > gemmB) before = gemmB;
        int cb = bid - before;
        int e = cb * 256 + threadIdx.x;
        if (e >= E) return;
        int d = dst[e];
        csr_src[row_ptr[d] + blk_sum[d >> 10] + erank[e]] = src[e];
        return;
    }
    // ----- GEMM path -----
    const int lane = threadIdx.x & 63;
    const int wid = (g9 * 256 + threadIdx.x) >> 6;
    const int n0 = wid * 32;
    if (n0 >= N) return;
    const int q = lane >> 4;
    const int fl = lane & 15;

    int r0 = n0 + fl;       if (r0 >= N) r0 = N - 1;
    int r1 = n0 + 16 + fl;  if (r1 >= N) r1 = N - 1;
    const float* xp0 = x + (size_t)r0 * F_IN + q * 8;
    const float* xp1 = x + (size_t)r1 * F_IN + q * 8;

    floatx4 acc[2][4];
#pragma unroll
    for (int t = 0; t < 2; ++t)
#pragma unroll
        for (int fb = 0; fb < 4; ++fb) acc[t][fb] = (floatx4){0.f, 0.f, 0.f, 0.f};

    const bf16x8* whv = (const bf16x8*)whf;
    const bf16x8* wlv = (const bf16x8*)wlf;

    // depth-2 pipeline: preload stage 0
    float4 na = *(const float4*)(xp0);
    float4 nb = *(const float4*)(xp0 + 4);
    float4 nc = *(const float4*)(xp1);
    float4 nd = *(const float4*)(xp1 + 4);

    for (int kb = 0; kb < NSTAGE - 1; ++kb) {
        float4 a = na, b = nb, c = nc, d = nd;
        if (kb + 1 < NSTAGE - 1) {  // issue next stage's loads before MFMA
            na = *(const float4*)(xp0 + (kb + 1) * 32);
            nb = *(const float4*)(xp0 + (kb + 1) * 32 + 4);
            nc = *(const float4*)(xp1 + (kb + 1) * 32);
            nd = *(const float4*)(xp1 + (kb + 1) * 32 + 4);
        }
        float xv0[8] = {a.x, a.y, a.z, a.w, b.x, b.y, b.z, b.w};
        float xv1[8] = {c.x, c.y, c.z, c.w, d.x, d.y, d.z, d.w};
        bf16x8 xh0, xl0, xh1, xl1;
#pragma unroll
        for (int j = 0; j < 8; ++j) {
            unsigned int b0 = __float_as_uint(xv0[j]);
            xh0[j] = (short)(b0 >> 16);
            float res0 = xv0[j] - __uint_as_float(b0 & 0xffff0000u);
            xl0[j] = (short)(__float_as_uint(res0) >> 16);
            unsigned int b1 = __float_as_uint(xv1[j]);
            xh1[j] = (short)(b1 >> 16);
            float res1 = xv1[j] - __uint_as_float(b1 & 0xffff0000u);
            xl1[j] = (short)(__float_as_uint(res1) >> 16);
        }
#pragma unroll
        for (int fb = 0; fb < 4; ++fb) {
            bf16x8 bh = whv[(size_t)(kb * 4 + fb) * 64 + lane];
            bf16x8 bl = wlv[(size_t)(kb * 4 + fb) * 64 + lane];
            acc[0][fb] = __builtin_amdgcn_mfma_f32_16x16x32_bf16(xh0, bh, acc[0][fb], 0, 0, 0);
            acc[0][fb] = __builtin_amdgcn_mfma_f32_16x16x32_bf16(xl0, bh, acc[0][fb], 0, 0, 0);
            acc[0][fb] = __builtin_amdgcn_mfma_f32_16x16x32_bf16(xh0, bl, acc[0][fb], 0, 0, 0);
            acc[1][fb] = __builtin_amdgcn_mfma_f32_16x16x32_bf16(xh1, bh, acc[1][fb], 0, 0, 0);
            acc[1][fb] = __builtin_amdgcn_mfma_f32_16x16x32_bf16(xl1, bh, acc[1][fb], 0, 0, 0);
            acc[1][fb] = __builtin_amdgcn_mfma_f32_16x16x32_bf16(xh1, bl, acc[1][fb], 0, 0, 0);
        }
    }
    {   // tail stage kb = NSTAGE-1 (k 480..511, valid k < 500), guarded loads
        const int kb = NSTAGE - 1;
        float xv0[8], xv1[8];
#pragma unroll
        for (int j = 0; j < 8; ++j) {
            int kk = kb * 32 + q * 8 + j;
            xv0[j] = (kk < F_IN) ? xp0[kb * 32 + j] : 0.f;
            xv1[j] = (kk < F_IN) ? xp1[kb * 32 + j] : 0.f;
        }
        bf16x8 xh0, xl0, xh1, xl1;
#pragma unroll
        for (int j = 0; j < 8; ++j) {
            unsigned int b0 = __float_as_uint(xv0[j]);
            xh0[j] = (short)(b0 >> 16);
            float res0 = xv0[j] - __uint_as_float(b0 & 0xffff0000u);
            xl0[j] = (short)(__float_as_uint(res0) >> 16);
            unsigned int b1 = __float_as_uint(xv1[j]);
            xh1[j] = (short)(b1 >> 16);
            float res1 = xv1[j] - __uint_as_float(b1 & 0xffff0000u);
            xl1[j] = (short)(__float_as_uint(res1) >> 16);
        }
#pragma unroll
        for (int fb = 0; fb < 4; ++fb) {
            bf16x8 bh = whv[(size_t)(kb * 4 + fb) * 64 + lane];
            bf16x8 bl = wlv[(size_t)(kb * 4 + fb) * 64 + lane];
            acc[0][fb] = __builtin_amdgcn_mfma_f32_16x16x32_bf16(xh0, bh, acc[0][fb], 0, 0, 0);
            acc[0][fb] = __builtin_amdgcn_mfma_f32_16x16x32_bf16(xl0, bh, acc[0][fb], 0, 0, 0);
            acc[0][fb] = __builtin_amdgcn_mfma_f32_16x16x32_bf16(xh0, bl, acc[0][fb], 0, 0, 0);
            acc[1][fb] = __builtin_amdgcn_mfma_f32_16x16x32_bf16(xh1, bh, acc[1][fb], 0, 0, 0);
            acc[1][fb] = __builtin_amdgcn_mfma_f32_16x16x32_bf16(xl1, bh, acc[1][fb], 0, 0, 0);
            acc[1][fb] = __builtin_amdgcn_mfma_f32_16x16x32_bf16(xh1, bl, acc[1][fb], 0, 0, 0);
        }
    }
#pragma unroll
    for (int t = 0; t < 2; ++t) {
#pragma unroll
        for (int r = 0; r < 4; ++r) {
            int node = n0 + t * 16 + q * 4 + r;
            if (node < N) {
                float dn = dis[node];
#pragma unroll
                for (int fb = 0; fb < 4; ++fb) {
                    h1b[(size_t)node * HDIM + fb * 16 + fl] =
                        f2bf(acc[t][fb][r] * dn);
                }
            }
        }
    }
}

// ---------------------------------------------------------------------------
// Stage 5: gather layer 1.  h1b rows pre-scaled by dis[s] -> pure adds.
// Wave per node, half-wave per edge parity, 8 edges in flight per half.
// ---------------------------------------------------------------------------
__global__ __launch_bounds__(256) void gather1_kernel(
        const int* __restrict__ row_ptr, const int* __restrict__ blk_sum,
        const int* __restrict__ csr_src, const float* __restrict__ dis,
        const unsigned short* __restrict__ h1b,
        float* __restrict__ agg1, int N) {
    int nid = blockIdx.x * 4 + (threadIdx.x >> 6);
    if (nid >= N) return;
    int node = __builtin_amdgcn_readfirstlane(nid);
    int lane = threadIdx.x & 63;
    int half = lane >> 5;
    int c = lane & 31;  // features 2c, 2c+1
    int beg = row_ptr[node] + blk_sum[node >> 10];
    int end = row_ptr[node + 1] + blk_sum[(node + 1) >> 10];
    float dd = dis[node];
    float a0 = 0.f, a1 = 0.f;
    if (half == 0) {  // self-loop: row already holds h1*dis[node]
        unsigned int w = *reinterpret_cast<const unsigned int*>(
            h1b + (size_t)node * HDIM + 2 * c);
        a0 = bflo(w);
        a1 = bfhi(w);
    }
    int p = beg + half;
    for (; p + 14 < end; p += 16) {  // 8 edges in flight per half
        unsigned int wv[8];
#pragma unroll
        for (int i = 0; i < 8; ++i) {
            int s = csr_src[p + 2 * i];
            wv[i] = *reinterpret_cast<const unsigned int*>(
                h1b + (size_t)s * HDIM + 2 * c);
        }
#pragma unroll
        for (int i = 0; i < 8; ++i) {
            a0 += bflo(wv[i]);
            a1 += bfhi(wv[i]);
        }
    }
    for (; p < end; p += 2) {
        int s0 = csr_src[p];
        unsigned int w0 = *reinterpret_cast<const unsigned int*>(
            h1b + (size_t)s0 * HDIM + 2 * c);
        a0 += bflo(w0);
        a1 += bfhi(w0);
    }
    a0 += __shfl_xor(a0, 32);
    a1 += __shfl_xor(a1, 32);
    if (half == 0) {
        *reinterpret_cast<float2*>(agg1 + (size_t)node * HDIM + 2 * c) =
            make_float2(a0 * dd, a1 * dd);
    }
}

// ---------------------------------------------------------------------------
// Stage 6: layer 2 dense: t = relu(agg1+b1); h2s[n] = (t @ W2) * dis[n],
// row stride 16 (pad never read downstream).
// ---------------------------------------------------------------------------
__global__ void layer2_kernel(const float* __restrict__ agg1,
                              const float* __restrict__ b1,
                              const float* __restrict__ W2,
                              const float* __restrict__ dis,
                              float* __restrict__ h2s, int N) {
    int n = blockIdx.x * blockDim.x + threadIdx.x;
    if (n >= N) return;
    const float* ar = agg1 + (size_t)n * HDIM;
    float t[HDIM];
#pragma unroll
    for (int c = 0; c < HDIM; ++c) {
        float v = ar[c] + b1[c];
        t[c] = v > 0.f ? v : 0.f;
    }
    float dn = dis[n];
    float* h2r = h2s + (size_t)n * H2LD;
#pragma unroll
    for (int j = 0; j < CDIM; ++j) {
        float acc = 0.f;
#pragma unroll
        for (int c = 0; c < HDIM; ++c) acc = fmaf(t[c], W2[c * CDIM + j], acc);
        h2r[j] = acc * dn;
    }
}

// ---------------------------------------------------------------------------
// Stage 7: gather layer 2.  Wave per node, 4 groups x 16 lanes, 4 edges in
// flight per group; h2s rows 64-B aligned; shfl reduce; bias + self at end.
// ---------------------------------------------------------------------------
__global__ __launch_bounds__(256) void gather2_kernel(
        const int* __restrict__ row_ptr, const int* __restrict__ blk_sum,
        const int* __restrict__ csr_src, const float* __restrict__ dis,
        const float* __restrict__ h2s, const float* __restrict__ b2,
        float* __restrict__ out, int N) {
    int nid = blockIdx.x * 4 + (threadIdx.x >> 6);
    if (nid >= N) return;
    int node = __builtin_amdgcn_readfirstlane(nid);
    int lane = threadIdx.x & 63;
    int g = lane >> 4;
    int j = lane & 15;
    int beg = row_ptr[node] + blk_sum[node >> 10];
    int end = row_ptr[node + 1] + blk_sum[(node + 1) >> 10];
    float acc = 0.f;
    int p = beg + g;
    for (; p + 12 < end; p += 16) {  // 4 edges in flight per group
        int s0 = csr_src[p];
        int s1 = csr_src[p + 4];
        int s2 = csr_src[p + 8];
        int s3 = csr_src[p + 12];
        float v0 = (j < CDIM) ? h2s[(size_t)s0 * H2LD + j] : 0.f;
        float v1 = (j < CDIM) ? h2s[(size_t)s1 * H2LD + j] : 0.f;
        float v2 = (j < CDIM) ? h2s[(size_t)s2 * H2LD + j] : 0.f;
        float v3 = (j < CDIM) ? h2s[(size_t)s3 * H2LD + j] : 0.f;
        acc += (v0 + v1) + (v2 + v3);
    }
    for (; p < end; p += 4) {
        int s0 = csr_src[p];
        acc += (j < CDIM) ? h2s[(size_t)s0 * H2LD + j] : 0.f;
    }
    acc += __shfl_xor(acc, 16);
    acc += __shfl_xor(acc, 32);
    if (lane < CDIM) {
        float dd = dis[node];
        out[(size_t)node * CDIM + lane] =
            b2[lane] + dd * (acc + h2s[(size_t)node * H2LD + lane]);
    }
}

// ---------------------------------------------------------------------------
static inline char* align256(char* p) {
    return (char*)(((uintptr_t)p + 255) & ~(uintptr_t)255);
}

extern "C" void kernel_launch(void* const* d_in, const int* in_sizes, int n_in,
                              void* d_out, int out_size, void* d_ws,
                              size_t ws_size, hipStream_t stream) {
    const float* x  = (const float*)d_in[0];
    const int*   ei = (const int*)d_in[1];
    const float* W1 = (const float*)d_in[2];
    const float* b1 = (const float*)d_in[3];
    const float* W2 = (const float*)d_in[4];
    const float* b2 = (const float*)d_in[5];

    const int N = in_sizes[0] / F_IN;   // 100000
    const int E = in_sizes[1] / 2;      // 1600000
    const int* src = ei;
    const int* dst = ei + E;
    float* out = (float*)d_out;

    const int Np1 = N + 1;
    const int nscan_blocks = (Np1 + 1023) / 1024;

    // workspace layout (~38 MB), 256B-aligned chunks
    char* w = (char*)d_ws;
    int* deg = (int*)w;                  w = align256(w + (size_t)N * 4);  // zeroed
    char* zero_end = w;
    int* erank = (int*)w;                w = align256(w + (size_t)E * 4);
    float* dis = (float*)w;              w = align256(w + (size_t)N * 4);
    int* row_ptr = (int*)w;              w = align256(w + (size_t)(N + 4) * 4);
    int* blk_sum = (int*)w;              w = align256(w + (size_t)nscan_blocks * 4);
    int* csr_src = (int*)w;              w = align256(w + (size_t)E * 4);
    unsigned short* whf = (unsigned short*)w;  w = align256(w + (size_t)KPAD * HDIM * 2);
    unsigned short* wlf = (unsigned short*)w;  w = align256(w + (size_t)KPAD * HDIM * 2);
    unsigned short* h1b = (unsigned short*)w;  w = align256(w + (size_t)N * HDIM * 2);
    float* agg1 = (float*)w;             w = align256(w + (size_t)N * HDIM * 4);
    float* h2s = (float*)w;              w = align256(w + (size_t)N * H2LD * 4);

    hipMemsetAsync(deg, 0, (size_t)(zero_end - (char*)deg), stream);  // deg only

    const int degB = (E + 255) / 256;                    // 6250
    const int wprepB = (KPAD * HDIM + 255) / 256;        // 128
    prep_kernel<<<degB + wprepB, 256, 0, stream>>>(dst, E, deg, erank, W1, whf,
                                                   wlf, degB);
    scan_block_kernel<<<nscan_blocks, 1024, 0, stream>>>(deg, row_ptr, blk_sum,
                                                         dis, Np1);
    scan_top_kernel<<<1, 64, 0, stream>>>(blk_sum, nscan_blocks);
    {
        int gemmB = ((N + 31) / 32 + 3) / 4;             // 782
        int csrB = (E + 255) / 256;                      // 6250
        csr_gemm_kernel<<<gemmB + csrB, 256, 0, stream>>>(
            x, whf, wlf, dis, h1b, N,
            src, dst, erank, row_ptr, blk_sum, csr_src, E, gemmB);
    }
    gather1_kernel<<<(N + 3) / 4, 256, 0, stream>>>(row_ptr, blk_sum, csr_src,
                                                    dis, h1b, agg1, N);
    layer2_kernel<<<(N + 255) / 256, 256, 0, stream>>>(agg1, b1, W2, dis, h2s,
                                                       N);
    gather2_kernel<<<(N + 3) / 4, 256, 0, stream>>>(row_ptr, blk_sum, csr_src,
                                                    dis, h2s, b2, out, N);
}